// Round 4
// baseline (212.978 us; speedup 1.0000x reference)
//
#include <hip/hip_runtime.h>
#include <math.h>

#define NH 12
#define DMODEL 768
#define DHEAD 64
#define BATCH 16
#define SEQ 512
#define NTOK (BATCH*SEQ)   // 8192
#define ATTN_SCALE 0.125f
#define LN_EPS 1e-3f
#define PADP 72            // padded LDS row length (shorts) for the P tile
#define NST 24             // K steps of 32 (K = 768)

typedef __attribute__((ext_vector_type(8))) short  bf16x8;
typedef __attribute__((ext_vector_type(4))) float  f32x4;

__device__ __forceinline__ unsigned short f2bf(float f) {
    unsigned int u = __float_as_uint(f);
    unsigned int r = (u + 0x7fffu + ((u >> 16) & 1u)) >> 16;
    return (unsigned short)r;
}

__device__ __forceinline__ void async_copy16(const void* g, void* l) {
    __builtin_amdgcn_global_load_lds((const __attribute__((address_space(1))) void*)g,
                                     (__attribute__((address_space(3))) void*)l,
                                     16, 0, 0);
}

#define SBAR() do { \
    __builtin_amdgcn_sched_barrier(0); \
    __builtin_amdgcn_s_barrier(); \
    __builtin_amdgcn_sched_barrier(0); \
} while (0)

// counted vmcnt with literal N (FIFO: waits until <= N own VMEM ops outstanding)
#define VMW(n) do { \
    __builtin_amdgcn_sched_barrier(0); \
    asm volatile("s_waitcnt vmcnt(" #n ")" ::: "memory"); \
    __builtin_amdgcn_sched_barrier(0); \
} while (0)

// ---------------------------------------------------------------------------
// Merged prep: blocks [0,6144) cast x fp32->bf16; blocks [6144,8448) build
// Wt[n][k] = bf16(W[k][n]) for the 4 weight matrices. (wtq/wtk/wtv are
// CONTIGUOUS in the workspace -> merged [2304][768] B matrix.)
// ---------------------------------------------------------------------------
__global__ __launch_bounds__(256) void prep_kernel(
    const float* __restrict__ x,
    const float* __restrict__ Wq, const float* __restrict__ Wk,
    const float* __restrict__ Wv, const float* __restrict__ Wo,
    unsigned short* __restrict__ xb,
    unsigned short* __restrict__ tq, unsigned short* __restrict__ tk,
    unsigned short* __restrict__ tv, unsigned short* __restrict__ to_)
{
    __shared__ float tile[32][33];
    const int bid = blockIdx.x;
    const int tid = threadIdx.x;

    if (bid < 6144) {
        int i = (bid * 256 + tid) * 4;
        const float4 v = *(const float4*)(x + i);
        unsigned long long pack =
              (unsigned long long)f2bf(v.x)
            | ((unsigned long long)f2bf(v.y) << 16)
            | ((unsigned long long)f2bf(v.z) << 32)
            | ((unsigned long long)f2bf(v.w) << 48);
        *(unsigned long long*)(xb + i) = pack;
        return;
    }

    const int t   = bid - 6144;       // 0..2303
    const int zz  = t / 576;
    const int rem = t % 576;
    const float* W = (zz == 0) ? Wq : (zz == 1) ? Wk : (zz == 2) ? Wv : Wo;
    unsigned short* T = (zz == 0) ? tq : (zz == 1) ? tk : (zz == 2) ? tv : to_;

    const int bx = (rem / 24) * 32;   // k base
    const int by = (rem % 24) * 32;   // n base
    const int tx = tid & 31, ty = tid >> 5;   // ty 0..7

    #pragma unroll
    for (int i = 0; i < 32; i += 8)
        tile[ty + i][tx] = W[(size_t)(bx + ty + i) * DMODEL + by + tx];
    __syncthreads();
    #pragma unroll
    for (int i = 0; i < 32; i += 8)
        T[(size_t)(by + ty + i) * DMODEL + bx + tx] = f2bf(tile[tx][ty + i]);
}

// ---------------------------------------------------------------------------
// qkv GEMM, triple-buffered BK=32 with COUNTED vmcnt (T4).
// BM=256 x BN=288 -> grid 32x8 = 256 blocks = 1/CU exact. 8 waves (4M x 2N,
// per-wave 64x144, acc[4][9]). Per step t: issue stage(t+2) (depth-2
// prefetch), 13 ds_read_b128 + 36 MFMA on buf[t%3], then s_waitcnt vmcnt(c)
// where c = own stage(t+2) count -> everything through stage(t+1) retired
// (FIFO), stage(t+2) still in flight; one s_barrier per step. Loads are never
// drained to 0 inside the loop (m218: counted-vs-drain0 is THE pipeline gain).
// BK=32 makes frag reads a contiguous 1KB rectangle (16 rows x 4 chunks) ->
// bank-conflict-free WITHOUT any swizzle; staging is linear.
// Race-free: each wave waits its own loads; the barrier joins all waves.
// ---------------------------------------------------------------------------
#define QSTAGE(kt, sb) do { \
    const int _k0 = (kt) * 32; \
    async_copy16(aS + _k0,                    &As[sb][(2 * w)     * 512]); \
    async_copy16(aS + 16 * DMODEL + _k0,      &As[sb][(2 * w + 1) * 512]); \
    async_copy16(bS + _k0,                    &Bs[sb][(2 * w)     * 512]); \
    async_copy16(bS + 16 * DMODEL + _k0,      &Bs[sb][(2 * w + 1) * 512]); \
    if (w < 2) \
        async_copy16(bS2 + _k0,               &Bs[sb][(16 + w)    * 512]); \
} while (0)

#define QSTEP(stepIdx, bc, sb) do { \
    const int _st = (stepIdx); \
    if (_st + 2 < NST) QSTAGE(_st + 2, sb); \
    bf16x8 aF[4], bF[9]; \
    _Pragma("unroll") \
    for (int _m = 0; _m < 4; ++_m) \
        aF[_m] = *(const bf16x8*)&As[bc][(wm * 64 + _m * 16 + l16) * 32 + quad * 8]; \
    _Pragma("unroll") \
    for (int _n = 0; _n < 9; ++_n) \
        bF[_n] = *(const bf16x8*)&Bs[bc][(wn * 144 + _n * 16 + l16) * 32 + quad * 8]; \
    __builtin_amdgcn_s_setprio(1); \
    _Pragma("unroll") \
    for (int _n = 0; _n < 9; ++_n) \
      _Pragma("unroll") \
      for (int _m = 0; _m < 4; ++_m) \
        acc[_m][_n] = __builtin_amdgcn_mfma_f32_16x16x32_bf16(aF[_m], bF[_n], acc[_m][_n], 0, 0, 0); \
    __builtin_amdgcn_s_setprio(0); \
    if (_st <= NST - 3)      { if (w < 2) VMW(5); else VMW(4); } \
    else if (_st == NST - 2) VMW(0); \
    if (_st < NST - 1) SBAR(); \
} while (0)

__global__ __launch_bounds__(512, 2) void gemm_tri_qkv(
    const unsigned short* __restrict__ xb, const unsigned short* __restrict__ wt,
    const float* __restrict__ bq, const float* __restrict__ bk, const float* __restrict__ bv,
    unsigned short* __restrict__ o0, unsigned short* __restrict__ o1,
    unsigned short* __restrict__ o2)
{
    __shared__ __align__(16) unsigned short As[3][256 * 32];
    __shared__ __align__(16) unsigned short Bs[3][288 * 32];

    // bijective XCD swizzle: 256 blocks = 8 XCDs x 32 contiguous tiles
    const int orig = blockIdx.x;
    const int wg   = (orig & 7) * 32 + (orig >> 3);
    const int m0   = (wg >> 3) * 256;     // 32 M-tiles
    const int n0   = (wg & 7) * 288;      // 8 N-tiles

    const int tid  = threadIdx.x;
    const int lane = tid & 63;
    const int w    = tid >> 6;            // 0..7
    const int wm   = w >> 1, wn = w & 1;  // 4M x 2N wave grid
    const int quad = lane >> 4;
    const int l16  = lane & 15;
    const int lr   = lane >> 2;           // staging: row-within-inst 0..15
    const int lc   = (lane & 3) * 8;      // staging: k-chunk (shorts)

    // staging sources (per-lane): wave w stages A rows [32w,32w+32) and
    // B rows [32w,32w+32) (+ rows 256+16w.. for w<2), 16 rows per inst.
    const unsigned short* aS  = xb + (size_t)(m0 + 32 * w + lr) * DMODEL + lc;
    const unsigned short* bS  = wt + (size_t)(n0 + 32 * w + lr) * DMODEL + lc;
    const unsigned short* bS2 = wt + (size_t)(n0 + 256 + 16 * w + lr) * DMODEL + lc;

    f32x4 acc[4][9] = {};

    // prologue: stage steps 0 and 1; wait own stage(0) done (vmcnt(c) leaves
    // stage(1) in flight), barrier joins all waves' stage(0).
    QSTAGE(0, 0);
    QSTAGE(1, 1);
    if (w < 2) VMW(5); else VMW(4);
    SBAR();

    #pragma unroll 1
    for (int tt = 0; tt < NST / 3; ++tt) {
        QSTEP(3 * tt + 0, 0, 2);
        QSTEP(3 * tt + 1, 1, 0);
        QSTEP(3 * tt + 2, 2, 1);
    }

    // epilogue: per 16-col group, pick q/k/v (wave-uniform: 16 | 768)
    #pragma unroll
    for (int nf = 0; nf < 9; ++nf) {
        const int ncg = n0 + wn * 144 + nf * 16 + l16;
        const int zz  = (ncg >= 1536) ? 2 : (ncg >= 768) ? 1 : 0;
        const int ncl = ncg - zz * 768;
        const int h = ncl >> 6, dh = ncl & 63;
        const float bval = ((zz == 0) ? bq : (zz == 1) ? bk : bv)[ncl];
        if (zz == 2) {
            // V^T layout: [B,H,DH,SEQ], pack 4 consecutive tokens per store
            #pragma unroll
            for (int mi = 0; mi < 4; ++mi) {
                const int mbase = m0 + wm * 64 + mi * 16 + quad * 4;
                const int bi = mbase >> 9, l = mbase & 511;
                unsigned long long pack = 0;
                #pragma unroll
                for (int r = 0; r < 4; ++r)
                    pack |= (unsigned long long)f2bf(acc[mi][nf][r] + bval) << (16 * r);
                *(unsigned long long*)(o2 + ((size_t)((bi * NH + h) * DHEAD + dh)) * SEQ + l) = pack;
            }
        } else {
            // Q/K layout: [B,H,SEQ,DH]; q pre-scaled by ATTN_SCALE
            const float sc = (zz == 0) ? ATTN_SCALE : 1.0f;
            unsigned short* out = (zz == 0) ? o0 : o1;
            #pragma unroll
            for (int mi = 0; mi < 4; ++mi) {
                const int mbase = m0 + wm * 64 + mi * 16 + quad * 4;
                #pragma unroll
                for (int r = 0; r < 4; ++r) {
                    const int t = mbase + r;
                    const int bi = t >> 9, l = t & 511;
                    out[(size_t)((bi * NH + h) * SEQ + l) * DHEAD + dh] =
                        f2bf((acc[mi][nf][r] + bval) * sc);
                }
            }
        }
    }
}

// ---------------------------------------------------------------------------
// O-proj: same triple-buffer BK=32 counted-vmcnt template.
// BM=128 x BN=192 -> grid 64x4 = 256 blocks = 1/CU exact. 8 waves
// (2M x 4N, per-wave 64x48, acc[4][3]). Epilogue: y = acc + bo + x (fp32).
// ---------------------------------------------------------------------------
#define OSTAGE(kt, sb) do { \
    const int _k0 = (kt) * 32; \
    async_copy16(aS + _k0,  &Ao[sb][w * 512]); \
    async_copy16(bS + _k0,  &Bo[sb][w * 512]); \
    if (w < 4) \
        async_copy16(bS2 + _k0, &Bo[sb][(8 + w) * 512]); \
} while (0)

#define OSTEP(stepIdx, bc, sb) do { \
    const int _st = (stepIdx); \
    if (_st + 2 < NST) OSTAGE(_st + 2, sb); \
    bf16x8 aF[4], bF[3]; \
    _Pragma("unroll") \
    for (int _m = 0; _m < 4; ++_m) \
        aF[_m] = *(const bf16x8*)&Ao[bc][(wm * 64 + _m * 16 + l16) * 32 + quad * 8]; \
    _Pragma("unroll") \
    for (int _n = 0; _n < 3; ++_n) \
        bF[_n] = *(const bf16x8*)&Bo[bc][(wn * 48 + _n * 16 + l16) * 32 + quad * 8]; \
    __builtin_amdgcn_s_setprio(1); \
    _Pragma("unroll") \
    for (int _n = 0; _n < 3; ++_n) \
      _Pragma("unroll") \
      for (int _m = 0; _m < 4; ++_m) \
        acc[_m][_n] = __builtin_amdgcn_mfma_f32_16x16x32_bf16(aF[_m], bF[_n], acc[_m][_n], 0, 0, 0); \
    __builtin_amdgcn_s_setprio(0); \
    if (_st <= NST - 3)      { if (w < 4) VMW(3); else VMW(2); } \
    else if (_st == NST - 2) VMW(0); \
    if (_st < NST - 1) SBAR(); \
} while (0)

__global__ __launch_bounds__(512, 2) void gemm_tri_oproj(
    const unsigned short* __restrict__ ctxb, const unsigned short* __restrict__ wto,
    const float* __restrict__ bo, const float* __restrict__ x,
    float* __restrict__ y)
{
    __shared__ __align__(16) unsigned short Ao[3][128 * 32];
    __shared__ __align__(16) unsigned short Bo[3][192 * 32];

    const int orig = blockIdx.x;
    const int wg   = (orig & 7) * 32 + (orig >> 3);   // 256 = 8 XCDs x 32
    const int m0   = (wg >> 2) * 128;                 // 64 M-tiles
    const int n0   = (wg & 3) * 192;                  // 4 N-tiles

    const int tid  = threadIdx.x;
    const int lane = tid & 63;
    const int w    = tid >> 6;            // 0..7
    const int wm   = w >> 2, wn = w & 3;  // 2M x 4N wave grid
    const int quad = lane >> 4;
    const int l16  = lane & 15;
    const int lr   = lane >> 2;
    const int lc   = (lane & 3) * 8;

    const unsigned short* aS  = ctxb + (size_t)(m0 + 16 * w + lr) * DMODEL + lc;
    const unsigned short* bS  = wto  + (size_t)(n0 + 16 * w + lr) * DMODEL + lc;
    const unsigned short* bS2 = wto  + (size_t)(n0 + 128 + 16 * w + lr) * DMODEL + lc;

    f32x4 acc[4][3] = {};

    OSTAGE(0, 0);
    OSTAGE(1, 1);
    if (w < 4) VMW(3); else VMW(2);
    SBAR();

    #pragma unroll 1
    for (int tt = 0; tt < NST / 3; ++tt) {
        OSTEP(3 * tt + 0, 0, 2);
        OSTEP(3 * tt + 1, 1, 0);
        OSTEP(3 * tt + 2, 2, 1);
    }

    #pragma unroll
    for (int ni = 0; ni < 3; ++ni) {
        const int ncol = n0 + wn * 48 + ni * 16 + l16;
        const float bv_ = bo[ncol];
        #pragma unroll
        for (int mi = 0; mi < 4; ++mi) {
            const int mbase = m0 + wm * 64 + mi * 16 + quad * 4;
            #pragma unroll
            for (int r = 0; r < 4; ++r) {
                const size_t idx = (size_t)(mbase + r) * DMODEL + ncol;
                y[idx] = acc[mi][ni][r] + bv_ + x[idx];
            }
        }
    }
}

// ---------------------------------------------------------------------------
// MFMA flash attention v4 (unchanged this round): no max-subtraction softmax,
// K/V double-buffered, l accumulated via ones-MFMA.
// ---------------------------------------------------------------------------
__global__ __launch_bounds__(256) void attn_mfma_kernel(
    const unsigned short* __restrict__ q, const unsigned short* __restrict__ k,
    const unsigned short* __restrict__ vt, const int* __restrict__ mask,
    unsigned short* __restrict__ ctxb)
{
    __shared__ __align__(16) unsigned short Qs[64 * 64];
    __shared__ __align__(16) unsigned short Ks[2][64 * 64];
    __shared__ __align__(16) unsigned short Vs[2][64 * 64];   // V^T: [d][key]
    __shared__ __align__(16) unsigned short Ps[64 * PADP];
    __shared__ float maskV[SEQ];
    __shared__ int   cleanS[8];

    const int tid  = threadIdx.x;
    const int lane = tid & 63;
    const int w    = tid >> 6;
    const int quad = lane >> 4;
    const int l16  = lane & 15;

    const int id = blockIdx.x;
    const int qt = id / (BATCH * NH);
    const int g  = id % (BATCH * NH);
    const int b  = g / NH, h = g % NH;
    const int q0 = qt * 64;

    const unsigned short* qp  = q  + ((size_t)(b * NH + h) * SEQ + q0) * DHEAD;
    const unsigned short* kp  = k  + (size_t)(b * NH + h) * SEQ * DHEAD;
    const unsigned short* vtp = vt + (size_t)(b * NH + h) * DHEAD * SEQ;

    const int rloc = lane >> 3;
    const int csw  = (lane & 7) ^ rloc;
    const int p0   = (quad ^ (l16 & 7)) * 8;

    #pragma unroll
    for (int ii = 0; ii < 2; ++ii) {
        const int inst = 2 * w + ii;
        async_copy16(qp  + (size_t)(inst * 8 + rloc) * DHEAD + csw * 8, Qs + inst * 512);
        async_copy16(kp  + (size_t)(inst * 8 + rloc) * DHEAD + csw * 8, &Ks[0][inst * 512]);
        async_copy16(vtp + (size_t)(inst * 8 + rloc) * SEQ + csw * 8,   &Vs[0][inst * 512]);
    }
    #pragma unroll
    for (int j = 0; j < 2; ++j) {
        const int idx = tid + 256 * j;
        const bool pm = mask[b * SEQ + idx] > 0;
        maskV[idx] = pm ? 0.f : -1e9f;
        const unsigned long long bb = __ballot(pm);
        if (lane == 0) cleanS[w + 4 * j] = (bb == ~0ull) ? 1 : 0;
    }
    __syncthreads();

    bf16x8 aQ[2];
    #pragma unroll
    for (int ks = 0; ks < 2; ++ks)
        aQ[ks] = *(const bf16x8*)&Qs[(w * 16 + l16) * 64 + (p0 ^ (ks * 32))];

    bf16x8 ones;
    #pragma unroll
    for (int j = 0; j < 8; ++j) ones[j] = (short)0x3F80;

    f32x4 o[4] = {};
    f32x4 lsum = {0.f, 0.f, 0.f, 0.f};
    const f32x4 zf = {0.f, 0.f, 0.f, 0.f};

    #pragma unroll
    for (int it = 0; it < 8; ++it) {
        const int cur = it & 1;
        if (it + 1 < 8) {
            const int kt1 = (it + 1) * 64;
            #pragma unroll
            for (int ii = 0; ii < 2; ++ii) {
                const int inst = 2 * w + ii;
                async_copy16(kp  + (size_t)(kt1 + inst * 8 + rloc) * DHEAD + csw * 8,
                             &Ks[1 - cur][inst * 512]);
                async_copy16(vtp + (size_t)(inst * 8 + rloc) * SEQ + kt1 + csw * 8,
                             &Vs[1 - cur][inst * 512]);
            }
        }
        const int kt = it * 64;

        f32x4 s[4];
        #pragma unroll
        for (int ni = 0; ni < 4; ++ni) {
            bf16x8 bK0 = *(const bf16x8*)&Ks[cur][(ni * 16 + l16) * 64 + p0];
            bf16x8 bK1 = *(const bf16x8*)&Ks[cur][(ni * 16 + l16) * 64 + (p0 ^ 32)];
            f32x4 t0 = __builtin_amdgcn_mfma_f32_16x16x32_bf16(aQ[0], bK0, zf, 0, 0, 0);
            s[ni] = __builtin_amdgcn_mfma_f32_16x16x32_bf16(aQ[1], bK1, t0, 0, 0, 0);
        }
        if (cleanS[it] == 0) {
            #pragma unroll
            for (int ni = 0; ni < 4; ++ni) {
                const float mk = maskV[kt + ni * 16 + l16];
                #pragma unroll
                for (int r = 0; r < 4; ++r) s[ni][r] += mk;
            }
        }

        #pragma unroll
        for (int ni = 0; ni < 4; ++ni)
            #pragma unroll
            for (int r = 0; r < 4; ++r)
                Ps[(w * 16 + quad * 4 + r) * PADP + ni * 16 + l16]
                    = (unsigned short)(__float_as_uint(__expf(s[ni][r])) >> 16);

        bf16x8 aP[2];
        #pragma unroll
        for (int ks = 0; ks < 2; ++ks)
            aP[ks] = *(const bf16x8*)&Ps[(w * 16 + l16) * PADP + quad * 8 + ks * 32];

        lsum = __builtin_amdgcn_mfma_f32_16x16x32_bf16(aP[0], ones, lsum, 0, 0, 0);
        lsum = __builtin_amdgcn_mfma_f32_16x16x32_bf16(aP[1], ones, lsum, 0, 0, 0);

        #pragma unroll
        for (int ni = 0; ni < 4; ++ni) {
            bf16x8 bV0 = *(const bf16x8*)&Vs[cur][(ni * 16 + l16) * 64 + p0];
            bf16x8 bV1 = *(const bf16x8*)&Vs[cur][(ni * 16 + l16) * 64 + (p0 ^ 32)];
            o[ni] = __builtin_amdgcn_mfma_f32_16x16x32_bf16(aP[0], bV0, o[ni], 0, 0, 0);
            o[ni] = __builtin_amdgcn_mfma_f32_16x16x32_bf16(aP[1], bV1, o[ni], 0, 0, 0);
        }

        __syncthreads();
    }

    #pragma unroll
    for (int r = 0; r < 4; ++r) {
        const float inv = 1.f / lsum[r];
        const int tok = q0 + w * 16 + quad * 4 + r;
        #pragma unroll
        for (int ni = 0; ni < 4; ++ni)
            ctxb[(size_t)(b * SEQ + tok) * DMODEL + h * DHEAD + ni * 16 + l16]
                = f2bf(o[ni][r] * inv);
    }
}

// ---------------------------------------------------------------------------
// LayerNorm, in-place capable.
// ---------------------------------------------------------------------------
__global__ __launch_bounds__(256) void ln_kernel(
    const float* __restrict__ y, const float* __restrict__ gamma,
    const float* __restrict__ beta, float* __restrict__ out)
{
    const int t   = blockIdx.x;
    const int tid = threadIdx.x;
    const float* row = y + (size_t)t * DMODEL;

    float vals[3];
    float s = 0.f, s2 = 0.f;
    #pragma unroll
    for (int i = 0; i < 3; ++i) {
        float vv = row[tid + 256 * i];
        vals[i] = vv;
        s  += vv;
        s2 += vv * vv;
    }
    #pragma unroll
    for (int off = 32; off > 0; off >>= 1) {
        s  += __shfl_down(s,  off);
        s2 += __shfl_down(s2, off);
    }
    __shared__ float rbuf[8];
    int w = tid >> 6;
    if ((tid & 63) == 0) { rbuf[w] = s; rbuf[4 + w] = s2; }
    __syncthreads();
    float ts  = rbuf[0] + rbuf[1] + rbuf[2] + rbuf[3];
    float ts2 = rbuf[4] + rbuf[5] + rbuf[6] + rbuf[7];
    float mu  = ts * (1.f / DMODEL);
    float var = ts2 * (1.f / DMODEL) - mu * mu;
    float inv = rsqrtf(var + LN_EPS);
    #pragma unroll
    for (int i = 0; i < 3; ++i) {
        int c = tid + 256 * i;
        out[(size_t)t * DMODEL + c] = gamma[c] * (vals[i] - mu) * inv + beta[c];
    }
}

// ---------------------------------------------------------------------------
extern "C" void kernel_launch(void* const* d_in, const int* in_sizes, int n_in,
                              void* d_out, int out_size, void* d_ws, size_t ws_size,
                              hipStream_t stream) {
    const float* x     = (const float*)d_in[0];
    const int*   mask  = (const int*)  d_in[1];
    const float* Wq    = (const float*)d_in[2];
    const float* bq    = (const float*)d_in[3];
    const float* Wk    = (const float*)d_in[4];
    const float* bk    = (const float*)d_in[5];
    const float* Wv    = (const float*)d_in[6];
    const float* bv    = (const float*)d_in[7];
    const float* Wo    = (const float*)d_in[8];
    const float* bo    = (const float*)d_in[9];
    const float* gamma = (const float*)d_in[10];
    const float* beta  = (const float*)d_in[11];
    float* out = (float*)d_out;

    const size_t perTok = (size_t)NTOK * DMODEL;   // 6,291,456
    const size_t perW   = (size_t)DMODEL * DMODEL; //   589,824

    unsigned short* xb   = (unsigned short*)d_ws;
    unsigned short* wtq  = xb + perTok;            // wtq/wtk/wtv contiguous:
    unsigned short* wtk  = wtq + perW;             //   merged B = [2304][768]
    unsigned short* wtv  = wtk + perW;
    unsigned short* wto  = wtv + perW;
    unsigned short* qb   = wto + perW;
    unsigned short* kb   = qb + perTok;
    unsigned short* vb   = kb + perTok;            // holds V^T: [B,H,DH,SEQ]
    unsigned short* ctxb = vb + perTok;
    float* y = out;   // O-proj output lives in d_out; LN runs in-place

    prep_kernel<<<6144 + 2304, 256, 0, stream>>>(
        x, Wq, Wk, Wv, Wo, xb, wtq, wtk, wtv, wto);

    // merged QKV GEMM: [8192 x 768] x [768 x 2304], 256 blocks = 1/CU exact
    gemm_tri_qkv<<<256, 512, 0, stream>>>(xb, wtq, bq, bk, bv, qb, kb, vb);

    attn_mfma_kernel<<<dim3((SEQ / 64) * BATCH * NH), 256, 0, stream>>>(
        qb, kb, vb, mask, ctxb);

    // O-proj: [8192 x 768] x [768 x 768], 256 blocks = 1/CU exact
    gemm_tri_oproj<<<256, 512, 0, stream>>>(ctxb, wto, bo, x, y);

    ln_kernel<<<NTOK, 256, 0, stream>>>(y, gamma, beta, out);
}

// Round 5
// 194.392 us; speedup vs baseline: 1.0956x; 1.0956x over previous
//
#include <hip/hip_runtime.h>
#include <math.h>

#define NH 12
#define DMODEL 768
#define DHEAD 64
#define BATCH 16
#define SEQ 512
#define NTOK (BATCH*SEQ)   // 8192
#define ATTN_SCALE 0.125f
#define LN_EPS 1e-3f
#define PADP 72            // padded LDS row length (shorts) for the P tile
#define NKT 12             // K tiles of 64 (K = 768)

typedef __attribute__((ext_vector_type(8))) short  bf16x8;
typedef __attribute__((ext_vector_type(4))) float  f32x4;

__device__ __forceinline__ unsigned short f2bf(float f) {
    unsigned int u = __float_as_uint(f);
    unsigned int r = (u + 0x7fffu + ((u >> 16) & 1u)) >> 16;
    return (unsigned short)r;
}

__device__ __forceinline__ void async_copy16(const void* g, void* l) {
    __builtin_amdgcn_global_load_lds((const __attribute__((address_space(1))) void*)g,
                                     (__attribute__((address_space(3))) void*)l,
                                     16, 0, 0);
}

#define SBAR() do { \
    __builtin_amdgcn_sched_barrier(0); \
    __builtin_amdgcn_s_barrier(); \
    __builtin_amdgcn_sched_barrier(0); \
} while (0)

#define VMW0() do { \
    __builtin_amdgcn_sched_barrier(0); \
    asm volatile("s_waitcnt vmcnt(0)" ::: "memory"); \
    __builtin_amdgcn_sched_barrier(0); \
} while (0)

// ---------------------------------------------------------------------------
// Merged prep: blocks [0,6144) cast x fp32->bf16; blocks [6144,8448) build
// Wt[n][k] = bf16(W[k][n]) for the 4 weight matrices. (wtq/wtk/wtv are
// CONTIGUOUS in the workspace -> merged [2304][768] B matrix.)
// ---------------------------------------------------------------------------
__global__ __launch_bounds__(256) void prep_kernel(
    const float* __restrict__ x,
    const float* __restrict__ Wq, const float* __restrict__ Wk,
    const float* __restrict__ Wv, const float* __restrict__ Wo,
    unsigned short* __restrict__ xb,
    unsigned short* __restrict__ tq, unsigned short* __restrict__ tk,
    unsigned short* __restrict__ tv, unsigned short* __restrict__ to_)
{
    __shared__ float tile[32][33];
    const int bid = blockIdx.x;
    const int tid = threadIdx.x;

    if (bid < 6144) {
        int i = (bid * 256 + tid) * 4;
        const float4 v = *(const float4*)(x + i);
        unsigned long long pack =
              (unsigned long long)f2bf(v.x)
            | ((unsigned long long)f2bf(v.y) << 16)
            | ((unsigned long long)f2bf(v.z) << 32)
            | ((unsigned long long)f2bf(v.w) << 48);
        *(unsigned long long*)(xb + i) = pack;
        return;
    }

    const int t   = bid - 6144;       // 0..2303
    const int zz  = t / 576;
    const int rem = t % 576;
    const float* W = (zz == 0) ? Wq : (zz == 1) ? Wk : (zz == 2) ? Wv : Wo;
    unsigned short* T = (zz == 0) ? tq : (zz == 1) ? tk : (zz == 2) ? tv : to_;

    const int bx = (rem / 24) * 32;   // k base
    const int by = (rem % 24) * 32;   // n base
    const int tx = tid & 31, ty = tid >> 5;   // ty 0..7

    #pragma unroll
    for (int i = 0; i < 32; i += 8)
        tile[ty + i][tx] = W[(size_t)(bx + ty + i) * DMODEL + by + tx];
    __syncthreads();
    #pragma unroll
    for (int i = 0; i < 32; i += 8)
        T[(size_t)(by + ty + i) * DMODEL + bx + tx] = f2bf(tile[tx][ty + i]);
}

// ---------------------------------------------------------------------------
// qkv GEMM: BM=256 x BN=288, BK=64, double-buffered, grid 32x8 = 256 blocks
// = 1/CU exact (R2-proven geometry + XOR chunk swizzle, 0 bank conflicts).
// NEW vs R2: ONE barrier + one vmcnt wait per K-tile (12 total, was 36
// barriers). All fragment reads issue at tile head; the compiler interleaves
// MFMAs behind counted lgkmcnt (no mid-tile fences). Safety: every ds_read of
// buffer c is consumed by an MFMA before the tile-end barrier (lgkm forces
// completion), staging targets the other buffer, own-wave vmcnt(0) + barrier
// precede any read of the staged buffer. R4's BK=32 tri-buffer REGRESSED
// (64B row stride = 16 banks -> multiway conflicts, 2.56M counted); do not
// shrink BK below 64.
// ---------------------------------------------------------------------------
#define QSTAGE(kt, sb) do { \
    const int _k0 = (kt) * 64; \
    _Pragma("unroll") \
    for (int _i = 0; _i < 4; ++_i) \
        async_copy16(aSrc + (size_t)_i * (8 * DMODEL) + _k0, &As[sb][(w * 4 + _i) * 512]); \
    _Pragma("unroll") \
    for (int _i = 0; _i < 4; ++_i) \
        async_copy16(bSrc + (size_t)_i * (64 * DMODEL) + _k0, &Bs[sb][(w + 8 * _i) * 512]); \
    if (w < 4) \
        async_copy16(bSrc + (size_t)4 * (64 * DMODEL) + _k0, &Bs[sb][(w + 32) * 512]); \
} while (0)

#define QTILE(t, c, o, hasNext) do { \
    if (hasNext) QSTAGE((t) + 1, o); \
    bf16x8 aF[4][2]; \
    _Pragma("unroll") \
    for (int _m = 0; _m < 4; ++_m) { \
        const int _row = wm * 64 + _m * 16 + l16; \
        aF[_m][0] = *(const bf16x8*)&As[c][_row * 64 + p0]; \
        aF[_m][1] = *(const bf16x8*)&As[c][_row * 64 + (p0 ^ 32)]; \
    } \
    _Pragma("unroll") \
    for (int _nh = 0; _nh < 3; ++_nh) { \
        bf16x8 bF[3][2]; \
        _Pragma("unroll") \
        for (int _n = 0; _n < 3; ++_n) { \
            const int _row = wn * 144 + (_nh * 3 + _n) * 16 + l16; \
            bF[_n][0] = *(const bf16x8*)&Bs[c][_row * 64 + p0]; \
            bF[_n][1] = *(const bf16x8*)&Bs[c][_row * 64 + (p0 ^ 32)]; \
        } \
        __builtin_amdgcn_s_setprio(1); \
        _Pragma("unroll") \
        for (int _k = 0; _k < 2; ++_k) \
          _Pragma("unroll") \
          for (int _m = 0; _m < 4; ++_m) \
            _Pragma("unroll") \
            for (int _n = 0; _n < 3; ++_n) \
              acc[_m][_nh * 3 + _n] = __builtin_amdgcn_mfma_f32_16x16x32_bf16( \
                  aF[_m][_k], bF[_n][_k], acc[_m][_nh * 3 + _n], 0, 0, 0); \
        __builtin_amdgcn_s_setprio(0); \
    } \
    if (hasNext) VMW0(); \
    SBAR(); \
} while (0)

__global__ __launch_bounds__(512, 2) void gemm_db_qkv(
    const unsigned short* __restrict__ xb, const unsigned short* __restrict__ wt,
    const float* __restrict__ bq, const float* __restrict__ bk, const float* __restrict__ bv,
    unsigned short* __restrict__ o0, unsigned short* __restrict__ o1,
    unsigned short* __restrict__ o2)
{
    __shared__ __align__(16) unsigned short As[2][256 * 64];
    __shared__ __align__(16) unsigned short Bs[2][288 * 64];

    // bijective XCD swizzle: 256 blocks = 8 XCDs x 32 contiguous tiles
    const int orig = blockIdx.x;
    const int wg   = (orig & 7) * 32 + (orig >> 3);
    const int m0   = (wg >> 3) * 256;     // 32 M-tiles
    const int n0   = (wg & 7) * 288;      // 8 N-tiles

    const int tid  = threadIdx.x;
    const int lane = tid & 63;
    const int w    = tid >> 6;            // 0..7
    const int wm   = w >> 1, wn = w & 1;  // 4M x 2N wave grid
    const int quad = lane >> 4;
    const int l16  = lane & 15;
    const int rloc = lane >> 3;           // staging: row-within-inst 0..7
    const int csw  = (lane & 7) ^ rloc;   // swizzled logical chunk
    const int p0   = (quad ^ (l16 & 7)) * 8;

    const unsigned short* aSrc = xb + (size_t)(m0 + w * 32 + rloc) * DMODEL + csw * 8;
    const unsigned short* bSrc = wt + (size_t)(n0 + w * 8  + rloc) * DMODEL + csw * 8;

    f32x4 acc[4][9] = {};

    QSTAGE(0, 0);
    VMW0();
    SBAR();

    #pragma unroll 1
    for (int tt = 0; tt < NKT / 2; ++tt) {
        QTILE(2 * tt,     0, 1, 1);
        QTILE(2 * tt + 1, 1, 0, (tt < NKT / 2 - 1));
    }

    // epilogue: per 16-col group, pick q/k/v (wave-uniform: 16 | 768)
    #pragma unroll
    for (int nf = 0; nf < 9; ++nf) {
        const int ncg = n0 + wn * 144 + nf * 16 + l16;
        const int zz  = (ncg >= 1536) ? 2 : (ncg >= 768) ? 1 : 0;
        const int ncl = ncg - zz * 768;
        const int h = ncl >> 6, dh = ncl & 63;
        const float bval = ((zz == 0) ? bq : (zz == 1) ? bk : bv)[ncl];
        if (zz == 2) {
            // V^T layout: [B,H,DH,SEQ], pack 4 consecutive tokens per store
            #pragma unroll
            for (int mi = 0; mi < 4; ++mi) {
                const int mbase = m0 + wm * 64 + mi * 16 + quad * 4;
                const int bi = mbase >> 9, l = mbase & 511;
                unsigned long long pack = 0;
                #pragma unroll
                for (int r = 0; r < 4; ++r)
                    pack |= (unsigned long long)f2bf(acc[mi][nf][r] + bval) << (16 * r);
                *(unsigned long long*)(o2 + ((size_t)((bi * NH + h) * DHEAD + dh)) * SEQ + l) = pack;
            }
        } else {
            // Q/K layout: [B,H,SEQ,DH]; q pre-scaled by ATTN_SCALE
            const float sc = (zz == 0) ? ATTN_SCALE : 1.0f;
            unsigned short* out = (zz == 0) ? o0 : o1;
            #pragma unroll
            for (int mi = 0; mi < 4; ++mi) {
                const int mbase = m0 + wm * 64 + mi * 16 + quad * 4;
                #pragma unroll
                for (int r = 0; r < 4; ++r) {
                    const int t = mbase + r;
                    const int bi = t >> 9, l = t & 511;
                    out[(size_t)((bi * NH + h) * SEQ + l) * DHEAD + dh] =
                        f2bf((acc[mi][nf][r] + bval) * sc);
                }
            }
        }
    }
}

// ---------------------------------------------------------------------------
// O-proj: same template. BM=128 x BN=192 -> grid 64x4 = 256 blocks = 1/CU
// exact. 8 waves (2M x 4N, per-wave 64x48, acc[4][3]). A-rows padded to 132
// so LDS = 83 KB > 80 KB -> hardware can only fit 1 block/CU (deterministic
// balance). One barrier + one vmcnt per tile. Epilogue: y = acc + bo + x.
// ---------------------------------------------------------------------------
#define OSTAGE(kt, sb) do { \
    const int _k0 = (kt) * 64; \
    _Pragma("unroll") \
    for (int _i = 0; _i < 2; ++_i) \
        async_copy16(aSrc + (size_t)_i * (8 * DMODEL) + _k0, &Ao[sb][(w * 2 + _i) * 512]); \
    _Pragma("unroll") \
    for (int _i = 0; _i < 3; ++_i) \
        async_copy16(bSrc + (size_t)_i * (8 * DMODEL) + _k0, &Bo[sb][(w * 3 + _i) * 512]); \
} while (0)

#define OTILE(t, c, o, hasNext) do { \
    if (hasNext) OSTAGE((t) + 1, o); \
    bf16x8 aF[4][2], bF[3][2]; \
    _Pragma("unroll") \
    for (int _m = 0; _m < 4; ++_m) { \
        const int _row = wm * 64 + _m * 16 + l16; \
        aF[_m][0] = *(const bf16x8*)&Ao[c][_row * 64 + p0]; \
        aF[_m][1] = *(const bf16x8*)&Ao[c][_row * 64 + (p0 ^ 32)]; \
    } \
    _Pragma("unroll") \
    for (int _n = 0; _n < 3; ++_n) { \
        const int _row = wn * 48 + _n * 16 + l16; \
        bF[_n][0] = *(const bf16x8*)&Bo[c][_row * 64 + p0]; \
        bF[_n][1] = *(const bf16x8*)&Bo[c][_row * 64 + (p0 ^ 32)]; \
    } \
    __builtin_amdgcn_s_setprio(1); \
    _Pragma("unroll") \
    for (int _k = 0; _k < 2; ++_k) \
      _Pragma("unroll") \
      for (int _m = 0; _m < 4; ++_m) \
        _Pragma("unroll") \
        for (int _n = 0; _n < 3; ++_n) \
          acc[_m][_n] = __builtin_amdgcn_mfma_f32_16x16x32_bf16( \
              aF[_m][_k], bF[_n][_k], acc[_m][_n], 0, 0, 0); \
    __builtin_amdgcn_s_setprio(0); \
    if (hasNext) VMW0(); \
    SBAR(); \
} while (0)

__global__ __launch_bounds__(512, 2) void gemm_db_oproj(
    const unsigned short* __restrict__ ctxb, const unsigned short* __restrict__ wto,
    const float* __restrict__ bo, const float* __restrict__ x,
    float* __restrict__ y)
{
    __shared__ __align__(16) unsigned short Ao[2][132 * 64];   // 128 rows + pad
    __shared__ __align__(16) unsigned short Bo[2][192 * 64];

    const int orig = blockIdx.x;
    const int wg   = (orig & 7) * 32 + (orig >> 3);   // 256 = 8 XCDs x 32
    const int m0   = (wg >> 2) * 128;                 // 64 M-tiles
    const int n0   = (wg & 3) * 192;                  // 4 N-tiles

    const int tid  = threadIdx.x;
    const int lane = tid & 63;
    const int w    = tid >> 6;            // 0..7
    const int wm   = w >> 2, wn = w & 3;  // 2M x 4N wave grid
    const int quad = lane >> 4;
    const int l16  = lane & 15;
    const int rloc = lane >> 3;
    const int csw  = (lane & 7) ^ rloc;
    const int p0   = (quad ^ (l16 & 7)) * 8;

    const unsigned short* aSrc = ctxb + (size_t)(m0 + w * 16 + rloc) * DMODEL + csw * 8;
    const unsigned short* bSrc = wto  + (size_t)(n0 + w * 24 + rloc) * DMODEL + csw * 8;

    f32x4 acc[4][3] = {};

    OSTAGE(0, 0);
    VMW0();
    SBAR();

    #pragma unroll 1
    for (int tt = 0; tt < NKT / 2; ++tt) {
        OTILE(2 * tt,     0, 1, 1);
        OTILE(2 * tt + 1, 1, 0, (tt < NKT / 2 - 1));
    }

    #pragma unroll
    for (int ni = 0; ni < 3; ++ni) {
        const int ncol = n0 + wn * 48 + ni * 16 + l16;
        const float bv_ = bo[ncol];
        #pragma unroll
        for (int mi = 0; mi < 4; ++mi) {
            const int mbase = m0 + wm * 64 + mi * 16 + quad * 4;
            #pragma unroll
            for (int r = 0; r < 4; ++r) {
                const size_t idx = (size_t)(mbase + r) * DMODEL + ncol;
                y[idx] = acc[mi][ni][r] + bv_ + x[idx];
            }
        }
    }
}

// ---------------------------------------------------------------------------
// MFMA flash attention v4 (unchanged this round): no max-subtraction softmax,
// K/V double-buffered, l accumulated via ones-MFMA.
// ---------------------------------------------------------------------------
__global__ __launch_bounds__(256) void attn_mfma_kernel(
    const unsigned short* __restrict__ q, const unsigned short* __restrict__ k,
    const unsigned short* __restrict__ vt, const int* __restrict__ mask,
    unsigned short* __restrict__ ctxb)
{
    __shared__ __align__(16) unsigned short Qs[64 * 64];
    __shared__ __align__(16) unsigned short Ks[2][64 * 64];
    __shared__ __align__(16) unsigned short Vs[2][64 * 64];   // V^T: [d][key]
    __shared__ __align__(16) unsigned short Ps[64 * PADP];
    __shared__ float maskV[SEQ];
    __shared__ int   cleanS[8];

    const int tid  = threadIdx.x;
    const int lane = tid & 63;
    const int w    = tid >> 6;
    const int quad = lane >> 4;
    const int l16  = lane & 15;

    const int id = blockIdx.x;
    const int qt = id / (BATCH * NH);
    const int g  = id % (BATCH * NH);
    const int b  = g / NH, h = g % NH;
    const int q0 = qt * 64;

    const unsigned short* qp  = q  + ((size_t)(b * NH + h) * SEQ + q0) * DHEAD;
    const unsigned short* kp  = k  + (size_t)(b * NH + h) * SEQ * DHEAD;
    const unsigned short* vtp = vt + (size_t)(b * NH + h) * DHEAD * SEQ;

    const int rloc = lane >> 3;
    const int csw  = (lane & 7) ^ rloc;
    const int p0   = (quad ^ (l16 & 7)) * 8;

    #pragma unroll
    for (int ii = 0; ii < 2; ++ii) {
        const int inst = 2 * w + ii;
        async_copy16(qp  + (size_t)(inst * 8 + rloc) * DHEAD + csw * 8, Qs + inst * 512);
        async_copy16(kp  + (size_t)(inst * 8 + rloc) * DHEAD + csw * 8, &Ks[0][inst * 512]);
        async_copy16(vtp + (size_t)(inst * 8 + rloc) * SEQ + csw * 8,   &Vs[0][inst * 512]);
    }
    #pragma unroll
    for (int j = 0; j < 2; ++j) {
        const int idx = tid + 256 * j;
        const bool pm = mask[b * SEQ + idx] > 0;
        maskV[idx] = pm ? 0.f : -1e9f;
        const unsigned long long bb = __ballot(pm);
        if (lane == 0) cleanS[w + 4 * j] = (bb == ~0ull) ? 1 : 0;
    }
    __syncthreads();

    bf16x8 aQ[2];
    #pragma unroll
    for (int ks = 0; ks < 2; ++ks)
        aQ[ks] = *(const bf16x8*)&Qs[(w * 16 + l16) * 64 + (p0 ^ (ks * 32))];

    bf16x8 ones;
    #pragma unroll
    for (int j = 0; j < 8; ++j) ones[j] = (short)0x3F80;

    f32x4 o[4] = {};
    f32x4 lsum = {0.f, 0.f, 0.f, 0.f};
    const f32x4 zf = {0.f, 0.f, 0.f, 0.f};

    #pragma unroll
    for (int it = 0; it < 8; ++it) {
        const int cur = it & 1;
        if (it + 1 < 8) {
            const int kt1 = (it + 1) * 64;
            #pragma unroll
            for (int ii = 0; ii < 2; ++ii) {
                const int inst = 2 * w + ii;
                async_copy16(kp  + (size_t)(kt1 + inst * 8 + rloc) * DHEAD + csw * 8,
                             &Ks[1 - cur][inst * 512]);
                async_copy16(vtp + (size_t)(inst * 8 + rloc) * SEQ + kt1 + csw * 8,
                             &Vs[1 - cur][inst * 512]);
            }
        }
        const int kt = it * 64;

        f32x4 s[4];
        #pragma unroll
        for (int ni = 0; ni < 4; ++ni) {
            bf16x8 bK0 = *(const bf16x8*)&Ks[cur][(ni * 16 + l16) * 64 + p0];
            bf16x8 bK1 = *(const bf16x8*)&Ks[cur][(ni * 16 + l16) * 64 + (p0 ^ 32)];
            f32x4 t0 = __builtin_amdgcn_mfma_f32_16x16x32_bf16(aQ[0], bK0, zf, 0, 0, 0);
            s[ni] = __builtin_amdgcn_mfma_f32_16x16x32_bf16(aQ[1], bK1, t0, 0, 0, 0);
        }
        if (cleanS[it] == 0) {
            #pragma unroll
            for (int ni = 0; ni < 4; ++ni) {
                const float mk = maskV[kt + ni * 16 + l16];
                #pragma unroll
                for (int r = 0; r < 4; ++r) s[ni][r] += mk;
            }
        }

        #pragma unroll
        for (int ni = 0; ni < 4; ++ni)
            #pragma unroll
            for (int r = 0; r < 4; ++r)
                Ps[(w * 16 + quad * 4 + r) * PADP + ni * 16 + l16]
                    = (unsigned short)(__float_as_uint(__expf(s[ni][r])) >> 16);

        bf16x8 aP[2];
        #pragma unroll
        for (int ks = 0; ks < 2; ++ks)
            aP[ks] = *(const bf16x8*)&Ps[(w * 16 + l16) * PADP + quad * 8 + ks * 32];

        lsum = __builtin_amdgcn_mfma_f32_16x16x32_bf16(aP[0], ones, lsum, 0, 0, 0);
        lsum = __builtin_amdgcn_mfma_f32_16x16x32_bf16(aP[1], ones, lsum, 0, 0, 0);

        #pragma unroll
        for (int ni = 0; ni < 4; ++ni) {
            bf16x8 bV0 = *(const bf16x8*)&Vs[cur][(ni * 16 + l16) * 64 + p0];
            bf16x8 bV1 = *(const bf16x8*)&Vs[cur][(ni * 16 + l16) * 64 + (p0 ^ 32)];
            o[ni] = __builtin_amdgcn_mfma_f32_16x16x32_bf16(aP[0], bV0, o[ni], 0, 0, 0);
            o[ni] = __builtin_amdgcn_mfma_f32_16x16x32_bf16(aP[1], bV1, o[ni], 0, 0, 0);
        }

        __syncthreads();
    }

    #pragma unroll
    for (int r = 0; r < 4; ++r) {
        const float inv = 1.f / lsum[r];
        const int tok = q0 + w * 16 + quad * 4 + r;
        #pragma unroll
        for (int ni = 0; ni < 4; ++ni)
            ctxb[(size_t)(b * SEQ + tok) * DMODEL + h * DHEAD + ni * 16 + l16]
                = f2bf(o[ni][r] * inv);
    }
}

// ---------------------------------------------------------------------------
// LayerNorm, in-place capable.
// ---------------------------------------------------------------------------
__global__ __launch_bounds__(256) void ln_kernel(
    const float* __restrict__ y, const float* __restrict__ gamma,
    const float* __restrict__ beta, float* __restrict__ out)
{
    const int t   = blockIdx.x;
    const int tid = threadIdx.x;
    const float* row = y + (size_t)t * DMODEL;

    float vals[3];
    float s = 0.f, s2 = 0.f;
    #pragma unroll
    for (int i = 0; i < 3; ++i) {
        float vv = row[tid + 256 * i];
        vals[i] = vv;
        s  += vv;
        s2 += vv * vv;
    }
    #pragma unroll
    for (int off = 32; off > 0; off >>= 1) {
        s  += __shfl_down(s,  off);
        s2 += __shfl_down(s2, off);
    }
    __shared__ float rbuf[8];
    int w = tid >> 6;
    if ((tid & 63) == 0) { rbuf[w] = s; rbuf[4 + w] = s2; }
    __syncthreads();
    float ts  = rbuf[0] + rbuf[1] + rbuf[2] + rbuf[3];
    float ts2 = rbuf[4] + rbuf[5] + rbuf[6] + rbuf[7];
    float mu  = ts * (1.f / DMODEL);
    float var = ts2 * (1.f / DMODEL) - mu * mu;
    float inv = rsqrtf(var + LN_EPS);
    #pragma unroll
    for (int i = 0; i < 3; ++i) {
        int c = tid + 256 * i;
        out[(size_t)t * DMODEL + c] = gamma[c] * (vals[i] - mu) * inv + beta[c];
    }
}

// ---------------------------------------------------------------------------
extern "C" void kernel_launch(void* const* d_in, const int* in_sizes, int n_in,
                              void* d_out, int out_size, void* d_ws, size_t ws_size,
                              hipStream_t stream) {
    const float* x     = (const float*)d_in[0];
    const int*   mask  = (const int*)  d_in[1];
    const float* Wq    = (const float*)d_in[2];
    const float* bq    = (const float*)d_in[3];
    const float* Wk    = (const float*)d_in[4];
    const float* bk    = (const float*)d_in[5];
    const float* Wv    = (const float*)d_in[6];
    const float* bv    = (const float*)d_in[7];
    const float* Wo    = (const float*)d_in[8];
    const float* bo    = (const float*)d_in[9];
    const float* gamma = (const float*)d_in[10];
    const float* beta  = (const float*)d_in[11];
    float* out = (float*)d_out;

    const size_t perTok = (size_t)NTOK * DMODEL;   // 6,291,456
    const size_t perW   = (size_t)DMODEL * DMODEL; //   589,824

    unsigned short* xb   = (unsigned short*)d_ws;
    unsigned short* wtq  = xb + perTok;            // wtq/wtk/wtv contiguous:
    unsigned short* wtk  = wtq + perW;             //   merged B = [2304][768]
    unsigned short* wtv  = wtk + perW;
    unsigned short* wto  = wtv + perW;
    unsigned short* qb   = wto + perW;
    unsigned short* kb   = qb + perTok;
    unsigned short* vb   = kb + perTok;            // holds V^T: [B,H,DH,SEQ]
    unsigned short* ctxb = vb + perTok;
    float* y = out;   // O-proj output lives in d_out; LN runs in-place

    prep_kernel<<<6144 + 2304, 256, 0, stream>>>(
        x, Wq, Wk, Wv, Wo, xb, wtq, wtk, wtv, wto);

    // merged QKV GEMM: [8192 x 768] x [768 x 2304], 256 blocks = 1/CU exact
    gemm_db_qkv<<<256, 512, 0, stream>>>(xb, wtq, bq, bk, bv, qb, kb, vb);

    attn_mfma_kernel<<<dim3((SEQ / 64) * BATCH * NH), 256, 0, stream>>>(
        qb, kb, vb, mask, ctxb);

    // O-proj: [8192 x 768] x [768 x 768], 256 blocks = 1/CU exact
    gemm_db_oproj<<<256, 512, 0, stream>>>(ctxb, wto, bo, x, y);

    ln_kernel<<<NTOK, 256, 0, stream>>>(y, gamma, beta, out);
}